// Round 18
// baseline (226.488 us; speedup 1.0000x reference)
//
#include <hip/hip_runtime.h>

typedef unsigned short u16;
typedef __attribute__((ext_vector_type(8))) short s16x8;
typedef __attribute__((ext_vector_type(4))) short s16x4;
typedef __attribute__((ext_vector_type(8))) unsigned short u16x8;
typedef __attribute__((ext_vector_type(4))) unsigned short u16x4;
typedef __attribute__((ext_vector_type(4))) float f32x4;

#define B_ 2
#define S_ 2048
#define HID_ 2048
#define NH_ 32
#define NKV_ 8
#define HD_ 64
#define M_ (B_ * S_)          // 4096
#define NQKV_ 3072            // 2048 q + 512 k + 512 v

__device__ __forceinline__ u16 bf16rne(float f) {
    union { float f; unsigned u; } x; x.f = f;
    unsigned u = x.u;
    u += 0x7fffu + ((u >> 16) & 1u);
    return (u16)(u >> 16);
}
__device__ __forceinline__ float bf16tof(u16 h) {
    union { unsigned u; float f; } x; x.u = ((unsigned)h) << 16;
    return x.f;
}
__device__ __forceinline__ f32x4 vmax4(f32x4 a, f32x4 b) {
    f32x4 r;
    r[0] = fmaxf(a[0], b[0]); r[1] = fmaxf(a[1], b[1]);
    r[2] = fmaxf(a[2], b[2]); r[3] = fmaxf(a[3], b[3]);
    return r;
}
// packed f32->bf16 (RTZ). SAFE because l is MFMA-accumulated from the SAME
// truncated pa registers as O -- quotient bias cancels (verified r16).
__device__ __forceinline__ unsigned cvt_pk_bf16(float a, float b) {
    unsigned r;
    asm("v_cvt_pk_bf16_f32 %0, %1, %2" : "=v"(r) : "v"(a), "v"(b));
    return r;
}
__device__ __forceinline__ f32x4 mfma16x16x16_bf16(s16x4 a, s16x4 b, f32x4 c) {
#if __has_builtin(__builtin_amdgcn_mfma_f32_16x16x16bf16_1k)
    return __builtin_amdgcn_mfma_f32_16x16x16bf16_1k(a, b, c, 0, 0, 0);
#else
    f32x4 d = c;
    asm volatile("v_mfma_f32_16x16x16_bf16 %0, %1, %2, %0" : "+v"(d) : "v"(a), "v"(b));
    return d;
#endif
}

// async global->LDS, 16B per lane; LDS dest = wave-uniform base + lane*16
__device__ __forceinline__ void gload16(const void* g, void* l) {
    __builtin_amdgcn_global_load_lds(
        (const __attribute__((address_space(1))) unsigned int*)g,
        (__attribute__((address_space(3))) unsigned int*)l, 16, 0, 0);
}

// ---------------- fp32 -> bf16 convert (x) ----------------
__global__ __launch_bounds__(256) void convert_x_kernel(const float* __restrict__ src,
                                                        u16* __restrict__ dst, int n4) {
    int i = blockIdx.x * 256 + threadIdx.x;
    if (i >= n4) return;
    f32x4 v = *(const f32x4*)(src + (size_t)i * 4);
    u16x4 o;
    o[0] = bf16rne(v[0]); o[1] = bf16rne(v[1]); o[2] = bf16rne(v[2]); o[3] = bf16rne(v[3]);
    *(u16x4*)(dst + (size_t)i * 4) = o;
}

// ---------------- pack qkv bias (fp32) ----------------
__global__ void pack_bias_kernel(const float* bq, const float* bk, const float* bv,
                                 float* __restrict__ dst) {
    int i = blockIdx.x * 256 + threadIdx.x;
    if (i >= NQKV_) return;
    float v;
    if (i < 2048) v = bq[i];
    else if (i < 2560) v = bk[i - 2048];
    else v = bv[i - 2560];
    dst[i] = v;
}

// ---------------- all weight transposes in ONE dispatch ----------------
__global__ __launch_bounds__(256) void transpose_w_all_kernel(
    const float* __restrict__ Wq, const float* __restrict__ Wk,
    const float* __restrict__ Wv, const float* __restrict__ Wo,
    u16* __restrict__ wqkvT, u16* __restrict__ woT) {
    __shared__ float tile[32][33];
    int z = blockIdx.z;
    const float* src; u16* dst; int N;
    if (z == 0)      { src = Wq; dst = wqkvT;                          N = 2048; }
    else if (z == 1) { src = Wk; dst = wqkvT + (size_t)2048 * 2048;    N = 512;  }
    else if (z == 2) { src = Wv; dst = wqkvT + (size_t)2560 * 2048;    N = 512;  }
    else             { src = Wo; dst = woT;                            N = 2048; }
    int n0 = blockIdx.x * 32;
    if (n0 >= N) return;
    int k0 = blockIdx.y * 32;
    int tx = threadIdx.x;
    int ty = threadIdx.y;
    for (int i = 0; i < 32; i += 8)
        tile[ty + i][tx] = src[(size_t)(k0 + ty + i) * N + n0 + tx];
    __syncthreads();
    for (int i = 0; i < 32; i += 8)
        dst[(size_t)(n0 + ty + i) * 2048 + k0 + tx] = bf16rne(tile[tx][ty + i]);
}

// ---------------- bf16 GEMM (m97 structure + T1 XCD swizzle) ----------------
template <bool OUT_BF16, bool FUSE_VT>
__global__ __launch_bounds__(256) void gemm_bt_kernel(const u16* __restrict__ A,
                                                      const u16* __restrict__ Bt,
                                                      const float* __restrict__ bias,
                                                      void* __restrict__ Cout,
                                                      u16* __restrict__ vTp,
                                                      int M, int N, int K) {
    __shared__ u16 As[128][64];
    __shared__ u16 Bs[128][64];
    int nwg = (int)(gridDim.x * gridDim.y);
    int bid = (int)(blockIdx.y * gridDim.x + blockIdx.x);
    int swz = (bid & 7) * (nwg >> 3) + (bid >> 3);
    int bn = (swz % (int)gridDim.x) * 128;
    int bm = (swz / (int)gridDim.x) * 128;
    int tid = threadIdx.x;
    int lane = tid & 63, wid = tid >> 6;
    int wr = wid >> 1, wc = wid & 1;
    int lr = lane & 15, lg = lane >> 4;
    f32x4 acc[4][4] = {};

    int srow_l = lane >> 3;
    int schunk = (lane & 7) ^ srow_l;
    int scol = schunk * 8;

    for (int k0 = 0; k0 < K; k0 += 64) {
        __syncthreads();
#pragma unroll
        for (int c = 0; c < 4; c++) {
            int row = c * 32 + wid * 8;
            gload16(A + (size_t)(bm + row + srow_l) * K + k0 + scol, &As[row][0]);
            gload16(Bt + (size_t)(bn + row + srow_l) * K + k0 + scol, &Bs[row][0]);
        }
        asm volatile("s_waitcnt vmcnt(0)" ::: "memory");
        __syncthreads();
#pragma unroll
        for (int kk = 0; kk < 2; kk++) {
            s16x8 a[4], b[4];
#pragma unroll
            for (int mi = 0; mi < 4; mi++) {
                int row = wr * 64 + mi * 16 + lr;
                int cc = ((kk << 2) + lg) ^ (lr & 7);
                a[mi] = *(const s16x8*)&As[row][cc << 3];
            }
#pragma unroll
            for (int ni = 0; ni < 4; ni++) {
                int row = wc * 64 + ni * 16 + lr;
                int cc = ((kk << 2) + lg) ^ (lr & 7);
                b[ni] = *(const s16x8*)&Bs[row][cc << 3];
            }
#pragma unroll
            for (int mi = 0; mi < 4; mi++)
#pragma unroll
                for (int ni = 0; ni < 4; ni++)
                    acc[mi][ni] = __builtin_amdgcn_mfma_f32_16x16x32_bf16(a[mi], b[ni], acc[mi][ni], 0, 0, 0);
        }
    }

#pragma unroll
    for (int mi = 0; mi < 4; mi++)
#pragma unroll
        for (int ni = 0; ni < 4; ni++) {
            int col = bn + wc * 64 + ni * 16 + lr;
            float bsv = bias ? bias[col] : 0.0f;
            int row0 = bm + wr * 64 + mi * 16 + lg * 4;
            if (FUSE_VT && col >= 2560) {
                int kvd = col - 2560;
                int bq_ = row0 >> 11;
                int s0 = row0 & 2047;
                u16x4 w;
#pragma unroll
                for (int r = 0; r < 4; r++) w[r] = bf16rne(acc[mi][ni][r] + bsv);
                *(u16x4*)(vTp + (size_t)(bq_ * 8 * 64 + kvd) * 2048 + s0) = w;
            } else {
#pragma unroll
                for (int r = 0; r < 4; r++) {
                    float v = acc[mi][ni][r] + bsv;
                    if (OUT_BF16)
                        ((u16*)Cout)[(size_t)(row0 + r) * N + col] = bf16rne(v);
                    else
                        ((float*)Cout)[(size_t)(row0 + r) * N + col] = v;
                }
            }
        }
}

// ---------------- proj GEMM: 256x128 tile, BK=64, 8 waves, counted-vmcnt pipeline ----------
// out[M][2048] = attnO[M][2048] @ woT^T + bo (fp32 out). Grid 16x16=256 (perfect CU fill).
// Pipeline per K-tile: {issue 6 gloads into OTHER buf} -> vmcnt(6) (old 6 done, new fly
// across compute) -> barrier -> compute -> barrier (reads done; next iter may overwrite).
__global__ __launch_bounds__(512, 2) void gemm_proj256_kernel(const u16* __restrict__ A,
                                                              const u16* __restrict__ Bt,
                                                              const float* __restrict__ bias,
                                                              float* __restrict__ Cout) {
    __shared__ u16 As[2][256][64];   // 64 KB
    __shared__ u16 Bs[2][128][64];   // 32 KB
    const int K = HID_;
    int nwg = (int)(gridDim.x * gridDim.y);          // 256
    int bid = (int)(blockIdx.y * gridDim.x + blockIdx.x);
    int swz = (bid & 7) * (nwg >> 3) + (bid >> 3);   // T1 XCD swizzle
    int bn = (swz % (int)gridDim.x) * 128;
    int bm = (swz / (int)gridDim.x) * 256;
    int tid = threadIdx.x;
    int lane = tid & 63, wid = tid >> 6;             // 8 waves
    int wr = wid >> 2, wc = wid & 3;                 // 2 M-halves x 4 N-quarters
    int lr = lane & 15, lg = lane >> 4;
    f32x4 acc[8][2] = {};

    int srow_l = lane >> 3;                          // 0..7
    int schunk = (lane & 7) ^ srow_l;                // source-pre-swizzle (rule #21)
    int scol = schunk * 8;

#define STAGE_PROJ(buf, kk0)                                                        \
    {                                                                               \
        _Pragma("unroll")                                                           \
        for (int c = 0; c < 4; c++) {                                               \
            int row = c * 64 + wid * 8;                                             \
            gload16(A + (size_t)(bm + row + srow_l) * K + (kk0) + scol,             \
                    &As[buf][row][0]);                                              \
        }                                                                           \
        _Pragma("unroll")                                                           \
        for (int c = 0; c < 2; c++) {                                               \
            int row = c * 64 + wid * 8;                                             \
            gload16(Bt + (size_t)(bn + row + srow_l) * K + (kk0) + scol,            \
                    &Bs[buf][row][0]);                                              \
        }                                                                           \
    }

    // prologue
    STAGE_PROJ(0, 0);
    asm volatile("s_waitcnt vmcnt(0)" ::: "memory");
    __syncthreads();

    const int NT = K / 64;   // 32
    int cb = 0;
    for (int t = 0; t < NT; t++) {
        if (t + 1 < NT) {
            STAGE_PROJ(cb ^ 1, (t + 1) * 64);
            asm volatile("s_waitcnt vmcnt(6)" ::: "memory");  // old 6 done; new 6 in flight
        } else {
            asm volatile("s_waitcnt vmcnt(0)" ::: "memory");
        }
        __syncthreads();   // all waves' current-buffer loads landed
#pragma unroll
        for (int kk = 0; kk < 2; kk++) {
            s16x8 a[8], b[2];
            int cc = ((kk << 2) + lg) ^ (lr & 7);
#pragma unroll
            for (int mi = 0; mi < 8; mi++)
                a[mi] = *(const s16x8*)&As[cb][wr * 128 + mi * 16 + lr][cc << 3];
#pragma unroll
            for (int ni = 0; ni < 2; ni++)
                b[ni] = *(const s16x8*)&Bs[cb][wc * 32 + ni * 16 + lr][cc << 3];
            __builtin_amdgcn_s_setprio(1);
#pragma unroll
            for (int mi = 0; mi < 8; mi++)
#pragma unroll
                for (int ni = 0; ni < 2; ni++)
                    acc[mi][ni] = __builtin_amdgcn_mfma_f32_16x16x32_bf16(a[mi], b[ni], acc[mi][ni], 0, 0, 0);
            __builtin_amdgcn_s_setprio(0);
        }
        __syncthreads();   // reads of buf cb done; next iter may overwrite it
        cb ^= 1;
    }
#undef STAGE_PROJ

#pragma unroll
    for (int mi = 0; mi < 8; mi++)
#pragma unroll
        for (int ni = 0; ni < 2; ni++) {
            int col = bn + wc * 32 + ni * 16 + lr;
            float bsv = bias[col];
            int row0 = bm + wr * 128 + mi * 16 + lg * 4;
#pragma unroll
            for (int r = 0; r < 4; r++)
                Cout[(size_t)(row0 + r) * HID_ + col] = acc[mi][ni][r] + bsv;
        }
}

// ---------------- flash attention (r16 config -- validated 93.5us) ----------------
// 8 waves / 4 q-heads share staged K/V; paired causal q-tiles {bx, 63-bx}; KVBLK=64.
// Q prescaled by 0.125*log2(e); exp2-domain softmax; P<=1; skip-rescale; cvt_pk P pack
// with MFMA-accumulated l (ones-row).
__global__ __launch_bounds__(512) void attn_kernel(const u16* __restrict__ qkv,
                                                   const u16* __restrict__ vT,
                                                   u16* __restrict__ attn_out) {
    int bx = blockIdx.x;             // 0..31
    int bkv = blockIdx.y;            // 0..15
    int b = bkv >> 3, kvh = bkv & 7;
    int tid = threadIdx.x;
    int lane = tid & 63, wid = tid >> 6;   // 8 waves
    int lr = lane & 15, lg = lane >> 4;
    int h = kvh * 4 + (wid >> 1);    // q head: 2 waves per head
    int sub = wid & 1;               // 16-row subtile within the 32-row q-tile

    __shared__ u16 Ks[2][64][72];    // [buf][kv][d] padded (144B stride)
    __shared__ u16 Vs[2][64][72];    // [buf][d][kv] padded

    const u16* Kbase = qkv + (size_t)(b * S_) * NQKV_ + 2048 + kvh * 64;
    const u16* Vbase = vT + (size_t)(b * 8 + kvh) * 64 * S_;

    int srow = tid >> 3;             // 0..63 (one staging pass, 512 threads)
    int scol = (tid & 7) * 8;

    // ones A-fragment for the l-row: A[row=lr][k] = (lr==0) ? 1.0bf16 : 0
    s16x4 ones = {};
    if (lr == 0) {
        ones[0] = (short)0x3F80; ones[1] = (short)0x3F80;
        ones[2] = (short)0x3F80; ones[3] = (short)0x3F80;
    }

#pragma unroll 1
    for (int phase = 0; phase < 2; phase++) {
        int qt = phase ? (63 - bx) : bx;   // 32-row q-tile index
        int qrow0 = qt * 32 + sub * 16;    // this wave's first q row
        int nt = qt / 2 + 1;               // kv tiles of 64 covering causal extent

        // Q as B-fragment: lane holds Q[q=lr][d = db*32 + lg*8 + j], prescaled
        s16x8 qf[2];
        {
            const u16* qr = qkv + (size_t)(b * S_ + qrow0 + lr) * NQKV_ + h * 64;
#pragma unroll
            for (int db = 0; db < 2; db++) {
                u16x8 u = *(const u16x8*)(qr + db * 32 + lg * 8);
                s16x8 s;
#pragma unroll
                for (int j = 0; j < 8; j++) s[j] = (short)bf16rne(bf16tof(u[j]) * 0.18033688f);
                qf[db] = s;
            }
        }

        f32x4 O[4] = {};                 // O^T: O[dt] reg r = O[q=lr][d = 16dt + 4lg + r]
        f32x4 lacc = {};                 // l-row accumulator (lane lr at lg==0, reg 0)
        float m_i = -1e30f;              // running max for q-row (qrow0 + lr)

        // prologue: stage kv tile 0 into buf 0
        {
            u16x8 k0v = *(const u16x8*)(Kbase + (size_t)srow * NQKV_ + scol);
            u16x8 v0v = *(const u16x8*)(Vbase + (size_t)srow * S_ + scol);
            *(u16x8*)&Ks[0][srow][scol] = k0v;
            *(u16x8*)&Vs[0][srow][scol] = v0v;
        }
        __syncthreads();

        int cb = 0;
        for (int t = 0; t < nt; t++) {
            int kv0 = t * 64;
            bool notlast = (t + 1 < nt);
            // T14: issue next tile's global loads early (hide HBM/L2 under compute)
            u16x8 kn, vn;
            if (notlast) {
                kn = *(const u16x8*)(Kbase + (size_t)(kv0 + 64 + srow) * NQKV_ + scol);
                vn = *(const u16x8*)(Vbase + (size_t)srow * S_ + kv0 + 64 + scol);
            }

            // swapped QK^T: Sc[t4][r] = S[kv0+16t4+4lg+r][qrow0+lr]
            f32x4 Sc[4] = {};
            __builtin_amdgcn_s_setprio(1);
#pragma unroll
            for (int t4 = 0; t4 < 4; t4++) {
#pragma unroll
                for (int db = 0; db < 2; db++) {
                    s16x8 kf = *(const s16x8*)&Ks[cb][t4 * 16 + lr][db * 32 + lg * 8];
                    Sc[t4] = __builtin_amdgcn_mfma_f32_16x16x32_bf16(kf, qf[db], Sc[t4], 0, 0, 0);
                }
            }
            __builtin_amdgcn_s_setprio(0);
            // causal mask: only last tile is partial (block-uniform branch)
            if (t == nt - 1) {
                int qr = qrow0 + lr;
#pragma unroll
                for (int t4 = 0; t4 < 4; t4++)
#pragma unroll
                    for (int r = 0; r < 4; r++) {
                        int kvi = kv0 + t4 * 16 + lg * 4 + r;
                        Sc[t4][r] = (kvi <= qr) ? Sc[t4][r] : -1e30f;
                    }
            }
            // lane-local online softmax for q-row (qrow0+lr)
            f32x4 mm = vmax4(vmax4(Sc[0], Sc[1]), vmax4(Sc[2], Sc[3]));
            float mx = fmaxf(fmaxf(mm[0], mm[1]), fmaxf(mm[2], mm[3]));
            mx = fmaxf(mx, __shfl_xor(mx, 16));
            mx = fmaxf(mx, __shfl_xor(mx, 32));
            // skip-rescale: only when some lane's max grew (alpha==1 exactly otherwise)
            if (__any(mx > m_i)) {
                float newm = fmaxf(m_i, mx);
                float alpha = exp2f(m_i - newm);
                m_i = newm;
#pragma unroll
                for (int dt = 0; dt < 4; dt++)
#pragma unroll
                    for (int r = 0; r < 4; r++) O[dt][r] *= alpha;
#pragma unroll
                for (int r = 0; r < 4; r++) lacc[r] *= alpha;
            }
            f32x4 p4[4];
#pragma unroll
            for (int t4 = 0; t4 < 4; t4++)
#pragma unroll
                for (int r = 0; r < 4; r++)
                    p4[t4][r] = exp2f(Sc[t4][r] - m_i);
            // pack P via cvt_pk (8 ops); l comes from MFMA below using the same regs
            s16x4 pa[4];
#pragma unroll
            for (int t4 = 0; t4 < 4; t4++) {
                union { unsigned u[2]; s16x4 v; } uu;
                uu.u[0] = cvt_pk_bf16(p4[t4][0], p4[t4][1]);
                uu.u[1] = cvt_pk_bf16(p4[t4][2], p4[t4][3]);
                pa[t4] = uu.v;
            }
            // PV transposed: O^T += V^T * P; plus l-row via ones A-fragment
            __builtin_amdgcn_s_setprio(1);
#pragma unroll
            for (int t4 = 0; t4 < 4; t4++) {
#pragma unroll
                for (int dt = 0; dt < 4; dt++) {
                    s16x4 va = *(const s16x4*)&Vs[cb][dt * 16 + lr][t4 * 16 + lg * 4];
                    O[dt] = mfma16x16x16_bf16(va, pa[t4], O[dt]);
                }
                lacc = mfma16x16x16_bf16(ones, pa[t4], lacc);
            }
            __builtin_amdgcn_s_setprio(0);
            // write staged regs to the other buffer (nobody reads it this iter)
            if (notlast) {
                *(u16x8*)&Ks[cb ^ 1][srow][scol] = kn;
                *(u16x8*)&Vs[cb ^ 1][srow][scol] = vn;
            }
            __syncthreads();         // single barrier: staging visible + reads done
            cb ^= 1;
        }

        // epilogue: l[q=lr] lives at lane lr (lg==0), reg 0 of lacc
        float lv = __shfl(lacc[0], lr);
        float il = 1.0f / lv;
        u16* orow = attn_out + (size_t)(b * S_ + qrow0 + lr) * HID_ + h * 64 + lg * 4;
#pragma unroll
        for (int dt = 0; dt < 4; dt++) {
            u16x4 w;
#pragma unroll
            for (int r = 0; r < 4; r++) w[r] = bf16rne(O[dt][r] * il);
            *(u16x4*)(orow + dt * 16) = w;
        }
    }
}

extern "C" void kernel_launch(void* const* d_in, const int* in_sizes, int n_in,
                              void* d_out, int out_size, void* d_ws, size_t ws_size,
                              hipStream_t stream) {
    const float* x  = (const float*)d_in[0];
    // d_in[1] = mask (causal, implemented structurally)
    const float* Wq = (const float*)d_in[2];
    const float* bq = (const float*)d_in[3];
    const float* Wk = (const float*)d_in[4];
    const float* bk = (const float*)d_in[5];
    const float* Wv = (const float*)d_in[6];
    const float* bv = (const float*)d_in[7];
    const float* Wo = (const float*)d_in[8];
    const float* bo = (const float*)d_in[9];
    float* out = (float*)d_out;

    char* ws = (char*)d_ws;
    u16* xb     = (u16*)(ws);                              // 16.78 MB
    u16* wqkvT  = (u16*)(ws + 16777216);                   // 12.58 MB
    u16* woT    = (u16*)(ws + 29360128);                   // 8.39 MB
    u16* qkv    = (u16*)(ws + 37748736);                   // 25.17 MB
    u16* vT     = (u16*)(ws + 62914560);                   // 4.19 MB
    u16* attnO  = (u16*)(ws + 67108864);                   // 16.78 MB
    float* biasQ = (float*)(ws + 83886080);                // 12 KB

    // 1. convert x to bf16
    {
        int n4 = (M_ * HID_) / 4;
        convert_x_kernel<<<(n4 + 255) / 256, 256, 0, stream>>>(x, xb, n4);
    }
    // 2. pack qkv bias
    pack_bias_kernel<<<(NQKV_ + 255) / 256, 256, 0, stream>>>(bq, bk, bv, biasQ);
    // 3. all weight transposes in one dispatch
    transpose_w_all_kernel<<<dim3(64, 64, 4), dim3(32, 8), 0, stream>>>(
        Wq, Wk, Wv, Wo, wqkvT, woT);
    // 4. QKV GEMM (V slice -> vT directly)
    gemm_bt_kernel<true, true><<<dim3(NQKV_ / 128, M_ / 128), 256, 0, stream>>>(
        xb, wqkvT, biasQ, qkv, vT, M_, NQKV_, HID_);
    // 5. attention (r16 config): 512 blocks, KVBLK=64, paired causal q-tiles
    attn_kernel<<<dim3(32, B_ * NKV_), 512, 0, stream>>>(qkv, vT, attnO);
    // 6. output GEMM: 256x128 counted-vmcnt pipeline, 256 blocks (full CU fill)
    gemm_proj256_kernel<<<dim3(HID_ / 128, M_ / 256), 512, 0, stream>>>(
        attnO, woT, bo, out);
}

// Round 19
// 218.270 us; speedup vs baseline: 1.0376x; 1.0376x over previous
//
#include <hip/hip_runtime.h>

typedef unsigned short u16;
typedef __attribute__((ext_vector_type(8))) short s16x8;
typedef __attribute__((ext_vector_type(4))) short s16x4;
typedef __attribute__((ext_vector_type(8))) unsigned short u16x8;
typedef __attribute__((ext_vector_type(4))) unsigned short u16x4;
typedef __attribute__((ext_vector_type(4))) float f32x4;

#define B_ 2
#define S_ 2048
#define HID_ 2048
#define NH_ 32
#define NKV_ 8
#define HD_ 64
#define M_ (B_ * S_)          // 4096
#define NQKV_ 3072            // 2048 q + 512 k + 512 v

__device__ __forceinline__ u16 bf16rne(float f) {
    union { float f; unsigned u; } x; x.f = f;
    unsigned u = x.u;
    u += 0x7fffu + ((u >> 16) & 1u);
    return (u16)(u >> 16);
}
__device__ __forceinline__ float bf16tof(u16 h) {
    union { unsigned u; float f; } x; x.u = ((unsigned)h) << 16;
    return x.f;
}
__device__ __forceinline__ f32x4 vmax4(f32x4 a, f32x4 b) {
    f32x4 r;
    r[0] = fmaxf(a[0], b[0]); r[1] = fmaxf(a[1], b[1]);
    r[2] = fmaxf(a[2], b[2]); r[3] = fmaxf(a[3], b[3]);
    return r;
}
// packed f32->bf16 (RTZ). SAFE because l is MFMA-accumulated from the SAME
// truncated pa registers as O -- quotient bias cancels (verified r16).
__device__ __forceinline__ unsigned cvt_pk_bf16(float a, float b) {
    unsigned r;
    asm("v_cvt_pk_bf16_f32 %0, %1, %2" : "=v"(r) : "v"(a), "v"(b));
    return r;
}
__device__ __forceinline__ f32x4 mfma16x16x16_bf16(s16x4 a, s16x4 b, f32x4 c) {
#if __has_builtin(__builtin_amdgcn_mfma_f32_16x16x16bf16_1k)
    return __builtin_amdgcn_mfma_f32_16x16x16bf16_1k(a, b, c, 0, 0, 0);
#else
    f32x4 d = c;
    asm volatile("v_mfma_f32_16x16x16_bf16 %0, %1, %2, %0" : "+v"(d) : "v"(a), "v"(b));
    return d;
#endif
}

// async global->LDS, 16B per lane; LDS dest = wave-uniform base + lane*16
__device__ __forceinline__ void gload16(const void* g, void* l) {
    __builtin_amdgcn_global_load_lds(
        (const __attribute__((address_space(1))) unsigned int*)g,
        (__attribute__((address_space(3))) unsigned int*)l, 16, 0, 0);
}

// ---------------- fp32 -> bf16 convert (x) ----------------
__global__ __launch_bounds__(256) void convert_x_kernel(const float* __restrict__ src,
                                                        u16* __restrict__ dst, int n4) {
    int i = blockIdx.x * 256 + threadIdx.x;
    if (i >= n4) return;
    f32x4 v = *(const f32x4*)(src + (size_t)i * 4);
    u16x4 o;
    o[0] = bf16rne(v[0]); o[1] = bf16rne(v[1]); o[2] = bf16rne(v[2]); o[3] = bf16rne(v[3]);
    *(u16x4*)(dst + (size_t)i * 4) = o;
}

// ---------------- pack qkv bias (fp32) ----------------
__global__ void pack_bias_kernel(const float* bq, const float* bk, const float* bv,
                                 float* __restrict__ dst) {
    int i = blockIdx.x * 256 + threadIdx.x;
    if (i >= NQKV_) return;
    float v;
    if (i < 2048) v = bq[i];
    else if (i < 2560) v = bk[i - 2048];
    else v = bv[i - 2560];
    dst[i] = v;
}

// ---------------- all weight transposes in ONE dispatch ----------------
__global__ __launch_bounds__(256) void transpose_w_all_kernel(
    const float* __restrict__ Wq, const float* __restrict__ Wk,
    const float* __restrict__ Wv, const float* __restrict__ Wo,
    u16* __restrict__ wqkvT, u16* __restrict__ woT) {
    __shared__ float tile[32][33];
    int z = blockIdx.z;
    const float* src; u16* dst; int N;
    if (z == 0)      { src = Wq; dst = wqkvT;                          N = 2048; }
    else if (z == 1) { src = Wk; dst = wqkvT + (size_t)2048 * 2048;    N = 512;  }
    else if (z == 2) { src = Wv; dst = wqkvT + (size_t)2560 * 2048;    N = 512;  }
    else             { src = Wo; dst = woT;                            N = 2048; }
    int n0 = blockIdx.x * 32;
    if (n0 >= N) return;
    int k0 = blockIdx.y * 32;
    int tx = threadIdx.x;
    int ty = threadIdx.y;
    for (int i = 0; i < 32; i += 8)
        tile[ty + i][tx] = src[(size_t)(k0 + ty + i) * N + n0 + tx];
    __syncthreads();
    for (int i = 0; i < 32; i += 8)
        dst[(size_t)(n0 + ty + i) * 2048 + k0 + tx] = bf16rne(tile[tx][ty + i]);
}

// ---------------- bf16 GEMM (m97 structure + T1 XCD swizzle) ----------------
template <bool OUT_BF16, bool FUSE_VT>
__global__ __launch_bounds__(256) void gemm_bt_kernel(const u16* __restrict__ A,
                                                      const u16* __restrict__ Bt,
                                                      const float* __restrict__ bias,
                                                      void* __restrict__ Cout,
                                                      u16* __restrict__ vTp,
                                                      int M, int N, int K) {
    __shared__ u16 As[128][64];
    __shared__ u16 Bs[128][64];
    int nwg = (int)(gridDim.x * gridDim.y);
    int bid = (int)(blockIdx.y * gridDim.x + blockIdx.x);
    int swz = (bid & 7) * (nwg >> 3) + (bid >> 3);
    int bn = (swz % (int)gridDim.x) * 128;
    int bm = (swz / (int)gridDim.x) * 128;
    int tid = threadIdx.x;
    int lane = tid & 63, wid = tid >> 6;
    int wr = wid >> 1, wc = wid & 1;
    int lr = lane & 15, lg = lane >> 4;
    f32x4 acc[4][4] = {};

    int srow_l = lane >> 3;
    int schunk = (lane & 7) ^ srow_l;
    int scol = schunk * 8;

    for (int k0 = 0; k0 < K; k0 += 64) {
        __syncthreads();
#pragma unroll
        for (int c = 0; c < 4; c++) {
            int row = c * 32 + wid * 8;
            gload16(A + (size_t)(bm + row + srow_l) * K + k0 + scol, &As[row][0]);
            gload16(Bt + (size_t)(bn + row + srow_l) * K + k0 + scol, &Bs[row][0]);
        }
        asm volatile("s_waitcnt vmcnt(0)" ::: "memory");
        __syncthreads();
#pragma unroll
        for (int kk = 0; kk < 2; kk++) {
            s16x8 a[4], b[4];
#pragma unroll
            for (int mi = 0; mi < 4; mi++) {
                int row = wr * 64 + mi * 16 + lr;
                int cc = ((kk << 2) + lg) ^ (lr & 7);
                a[mi] = *(const s16x8*)&As[row][cc << 3];
            }
#pragma unroll
            for (int ni = 0; ni < 4; ni++) {
                int row = wc * 64 + ni * 16 + lr;
                int cc = ((kk << 2) + lg) ^ (lr & 7);
                b[ni] = *(const s16x8*)&Bs[row][cc << 3];
            }
#pragma unroll
            for (int mi = 0; mi < 4; mi++)
#pragma unroll
                for (int ni = 0; ni < 4; ni++)
                    acc[mi][ni] = __builtin_amdgcn_mfma_f32_16x16x32_bf16(a[mi], b[ni], acc[mi][ni], 0, 0, 0);
        }
    }

#pragma unroll
    for (int mi = 0; mi < 4; mi++)
#pragma unroll
        for (int ni = 0; ni < 4; ni++) {
            int col = bn + wc * 64 + ni * 16 + lr;
            float bsv = bias ? bias[col] : 0.0f;
            int row0 = bm + wr * 64 + mi * 16 + lg * 4;
            if (FUSE_VT && col >= 2560) {
                int kvd = col - 2560;
                int bq_ = row0 >> 11;
                int s0 = row0 & 2047;
                u16x4 w;
#pragma unroll
                for (int r = 0; r < 4; r++) w[r] = bf16rne(acc[mi][ni][r] + bsv);
                *(u16x4*)(vTp + (size_t)(bq_ * 8 * 64 + kvd) * 2048 + s0) = w;
            } else {
#pragma unroll
                for (int r = 0; r < 4; r++) {
                    float v = acc[mi][ni][r] + bsv;
                    if (OUT_BF16)
                        ((u16*)Cout)[(size_t)(row0 + r) * N + col] = bf16rne(v);
                    else
                        ((float*)Cout)[(size_t)(row0 + r) * N + col] = v;
                }
            }
        }
}

// ---------------- flash attention (r16 config -- validated 93.5us) ----------------
// 8 waves / 4 q-heads share staged K/V; paired causal q-tiles {bx, 63-bx}; KVBLK=64.
// Q prescaled by 0.125*log2(e); exp2-domain softmax; P<=1; skip-rescale; cvt_pk P pack
// with MFMA-accumulated l (ones-row).
__global__ __launch_bounds__(512) void attn_kernel(const u16* __restrict__ qkv,
                                                   const u16* __restrict__ vT,
                                                   u16* __restrict__ attn_out) {
    int bx = blockIdx.x;             // 0..31
    int bkv = blockIdx.y;            // 0..15
    int b = bkv >> 3, kvh = bkv & 7;
    int tid = threadIdx.x;
    int lane = tid & 63, wid = tid >> 6;   // 8 waves
    int lr = lane & 15, lg = lane >> 4;
    int h = kvh * 4 + (wid >> 1);    // q head: 2 waves per head
    int sub = wid & 1;               // 16-row subtile within the 32-row q-tile

    __shared__ u16 Ks[2][64][72];    // [buf][kv][d] padded (144B stride)
    __shared__ u16 Vs[2][64][72];    // [buf][d][kv] padded

    const u16* Kbase = qkv + (size_t)(b * S_) * NQKV_ + 2048 + kvh * 64;
    const u16* Vbase = vT + (size_t)(b * 8 + kvh) * 64 * S_;

    int srow = tid >> 3;             // 0..63 (one staging pass, 512 threads)
    int scol = (tid & 7) * 8;

    // ones A-fragment for the l-row: A[row=lr][k] = (lr==0) ? 1.0bf16 : 0
    s16x4 ones = {};
    if (lr == 0) {
        ones[0] = (short)0x3F80; ones[1] = (short)0x3F80;
        ones[2] = (short)0x3F80; ones[3] = (short)0x3F80;
    }

#pragma unroll 1
    for (int phase = 0; phase < 2; phase++) {
        int qt = phase ? (63 - bx) : bx;   // 32-row q-tile index
        int qrow0 = qt * 32 + sub * 16;    // this wave's first q row
        int nt = qt / 2 + 1;               // kv tiles of 64 covering causal extent

        // Q as B-fragment: lane holds Q[q=lr][d = db*32 + lg*8 + j], prescaled
        s16x8 qf[2];
        {
            const u16* qr = qkv + (size_t)(b * S_ + qrow0 + lr) * NQKV_ + h * 64;
#pragma unroll
            for (int db = 0; db < 2; db++) {
                u16x8 u = *(const u16x8*)(qr + db * 32 + lg * 8);
                s16x8 s;
#pragma unroll
                for (int j = 0; j < 8; j++) s[j] = (short)bf16rne(bf16tof(u[j]) * 0.18033688f);
                qf[db] = s;
            }
        }

        f32x4 O[4] = {};                 // O^T: O[dt] reg r = O[q=lr][d = 16dt + 4lg + r]
        f32x4 lacc = {};                 // l-row accumulator (lane lr at lg==0, reg 0)
        float m_i = -1e30f;              // running max for q-row (qrow0 + lr)

        // prologue: stage kv tile 0 into buf 0
        {
            u16x8 k0v = *(const u16x8*)(Kbase + (size_t)srow * NQKV_ + scol);
            u16x8 v0v = *(const u16x8*)(Vbase + (size_t)srow * S_ + scol);
            *(u16x8*)&Ks[0][srow][scol] = k0v;
            *(u16x8*)&Vs[0][srow][scol] = v0v;
        }
        __syncthreads();

        int cb = 0;
        for (int t = 0; t < nt; t++) {
            int kv0 = t * 64;
            bool notlast = (t + 1 < nt);
            // T14: issue next tile's global loads early (hide HBM/L2 under compute)
            u16x8 kn, vn;
            if (notlast) {
                kn = *(const u16x8*)(Kbase + (size_t)(kv0 + 64 + srow) * NQKV_ + scol);
                vn = *(const u16x8*)(Vbase + (size_t)srow * S_ + kv0 + 64 + scol);
            }

            // swapped QK^T: Sc[t4][r] = S[kv0+16t4+4lg+r][qrow0+lr]
            f32x4 Sc[4] = {};
            __builtin_amdgcn_s_setprio(1);
#pragma unroll
            for (int t4 = 0; t4 < 4; t4++) {
#pragma unroll
                for (int db = 0; db < 2; db++) {
                    s16x8 kf = *(const s16x8*)&Ks[cb][t4 * 16 + lr][db * 32 + lg * 8];
                    Sc[t4] = __builtin_amdgcn_mfma_f32_16x16x32_bf16(kf, qf[db], Sc[t4], 0, 0, 0);
                }
            }
            __builtin_amdgcn_s_setprio(0);
            // causal mask: only last tile is partial (block-uniform branch)
            if (t == nt - 1) {
                int qr = qrow0 + lr;
#pragma unroll
                for (int t4 = 0; t4 < 4; t4++)
#pragma unroll
                    for (int r = 0; r < 4; r++) {
                        int kvi = kv0 + t4 * 16 + lg * 4 + r;
                        Sc[t4][r] = (kvi <= qr) ? Sc[t4][r] : -1e30f;
                    }
            }
            // lane-local online softmax for q-row (qrow0+lr)
            f32x4 mm = vmax4(vmax4(Sc[0], Sc[1]), vmax4(Sc[2], Sc[3]));
            float mx = fmaxf(fmaxf(mm[0], mm[1]), fmaxf(mm[2], mm[3]));
            mx = fmaxf(mx, __shfl_xor(mx, 16));
            mx = fmaxf(mx, __shfl_xor(mx, 32));
            // skip-rescale: only when some lane's max grew (alpha==1 exactly otherwise)
            if (__any(mx > m_i)) {
                float newm = fmaxf(m_i, mx);
                float alpha = exp2f(m_i - newm);
                m_i = newm;
#pragma unroll
                for (int dt = 0; dt < 4; dt++)
#pragma unroll
                    for (int r = 0; r < 4; r++) O[dt][r] *= alpha;
#pragma unroll
                for (int r = 0; r < 4; r++) lacc[r] *= alpha;
            }
            f32x4 p4[4];
#pragma unroll
            for (int t4 = 0; t4 < 4; t4++)
#pragma unroll
                for (int r = 0; r < 4; r++)
                    p4[t4][r] = exp2f(Sc[t4][r] - m_i);
            // pack P via cvt_pk (8 ops); l comes from MFMA below using the same regs
            s16x4 pa[4];
#pragma unroll
            for (int t4 = 0; t4 < 4; t4++) {
                union { unsigned u[2]; s16x4 v; } uu;
                uu.u[0] = cvt_pk_bf16(p4[t4][0], p4[t4][1]);
                uu.u[1] = cvt_pk_bf16(p4[t4][2], p4[t4][3]);
                pa[t4] = uu.v;
            }
            // PV transposed: O^T += V^T * P; plus l-row via ones A-fragment
            __builtin_amdgcn_s_setprio(1);
#pragma unroll
            for (int t4 = 0; t4 < 4; t4++) {
#pragma unroll
                for (int dt = 0; dt < 4; dt++) {
                    s16x4 va = *(const s16x4*)&Vs[cb][dt * 16 + lr][t4 * 16 + lg * 4];
                    O[dt] = mfma16x16x16_bf16(va, pa[t4], O[dt]);
                }
                lacc = mfma16x16x16_bf16(ones, pa[t4], lacc);
            }
            __builtin_amdgcn_s_setprio(0);
            // write staged regs to the other buffer (nobody reads it this iter)
            if (notlast) {
                *(u16x8*)&Ks[cb ^ 1][srow][scol] = kn;
                *(u16x8*)&Vs[cb ^ 1][srow][scol] = vn;
            }
            __syncthreads();         // single barrier: staging visible + reads done
            cb ^= 1;
        }

        // epilogue: l[q=lr] lives at lane lr (lg==0), reg 0 of lacc
        float lv = __shfl(lacc[0], lr);
        float il = 1.0f / lv;
        u16* orow = attn_out + (size_t)(b * S_ + qrow0 + lr) * HID_ + h * 64 + lg * 4;
#pragma unroll
        for (int dt = 0; dt < 4; dt++) {
            u16x4 w;
#pragma unroll
            for (int r = 0; r < 4; r++) w[r] = bf16rne(O[dt][r] * il);
            *(u16x4*)(orow + dt * 16) = w;
        }
    }
}

extern "C" void kernel_launch(void* const* d_in, const int* in_sizes, int n_in,
                              void* d_out, int out_size, void* d_ws, size_t ws_size,
                              hipStream_t stream) {
    const float* x  = (const float*)d_in[0];
    // d_in[1] = mask (causal, implemented structurally)
    const float* Wq = (const float*)d_in[2];
    const float* bq = (const float*)d_in[3];
    const float* Wk = (const float*)d_in[4];
    const float* bk = (const float*)d_in[5];
    const float* Wv = (const float*)d_in[6];
    const float* bv = (const float*)d_in[7];
    const float* Wo = (const float*)d_in[8];
    const float* bo = (const float*)d_in[9];
    float* out = (float*)d_out;

    char* ws = (char*)d_ws;
    u16* xb     = (u16*)(ws);                              // 16.78 MB
    u16* wqkvT  = (u16*)(ws + 16777216);                   // 12.58 MB
    u16* woT    = (u16*)(ws + 29360128);                   // 8.39 MB
    u16* qkv    = (u16*)(ws + 37748736);                   // 25.17 MB
    u16* vT     = (u16*)(ws + 62914560);                   // 4.19 MB
    u16* attnO  = (u16*)(ws + 67108864);                   // 16.78 MB
    float* biasQ = (float*)(ws + 83886080);                // 12 KB

    // 1. convert x to bf16
    {
        int n4 = (M_ * HID_) / 4;
        convert_x_kernel<<<(n4 + 255) / 256, 256, 0, stream>>>(x, xb, n4);
    }
    // 2. pack qkv bias
    pack_bias_kernel<<<(NQKV_ + 255) / 256, 256, 0, stream>>>(bq, bk, bv, biasQ);
    // 3. all weight transposes in one dispatch
    transpose_w_all_kernel<<<dim3(64, 64, 4), dim3(32, 8), 0, stream>>>(
        Wq, Wk, Wv, Wo, wqkvT, woT);
    // 4. QKV GEMM (V slice -> vT directly)
    gemm_bt_kernel<true, true><<<dim3(NQKV_ / 128, M_ / 128), 256, 0, stream>>>(
        xb, wqkvT, biasQ, qkv, vT, M_, NQKV_, HID_);
    // 5. attention (r16 config): 512 blocks, KVBLK=64, paired causal q-tiles
    attn_kernel<<<dim3(32, B_ * NKV_), 512, 0, stream>>>(qkv, vT, attnO);
    // 6. output GEMM (m97 128^2 structure -- the 256x128 port regressed, reverted)
    gemm_bt_kernel<false, false><<<dim3(HID_ / 128, M_ / 128), 256, 0, stream>>>(
        attnO, woT, bo, out, nullptr, M_, HID_, HID_);
}

// Round 21
// 214.892 us; speedup vs baseline: 1.0540x; 1.0157x over previous
//
#include <hip/hip_runtime.h>

typedef unsigned short u16;
typedef __attribute__((ext_vector_type(8))) short s16x8;
typedef __attribute__((ext_vector_type(4))) short s16x4;
typedef __attribute__((ext_vector_type(8))) unsigned short u16x8;
typedef __attribute__((ext_vector_type(4))) unsigned short u16x4;
typedef __attribute__((ext_vector_type(4))) float f32x4;

#define B_ 2
#define S_ 2048
#define HID_ 2048
#define NH_ 32
#define NKV_ 8
#define HD_ 64
#define M_ (B_ * S_)          // 4096
#define NQKV_ 3072            // 2048 q + 512 k + 512 v

__device__ __forceinline__ u16 bf16rne(float f) {
    union { float f; unsigned u; } x; x.f = f;
    unsigned u = x.u;
    u += 0x7fffu + ((u >> 16) & 1u);
    return (u16)(u >> 16);
}
__device__ __forceinline__ float bf16tof(u16 h) {
    union { unsigned u; float f; } x; x.u = ((unsigned)h) << 16;
    return x.f;
}
__device__ __forceinline__ f32x4 vmax4(f32x4 a, f32x4 b) {
    f32x4 r;
    r[0] = fmaxf(a[0], b[0]); r[1] = fmaxf(a[1], b[1]);
    r[2] = fmaxf(a[2], b[2]); r[3] = fmaxf(a[3], b[3]);
    return r;
}
// packed f32->bf16 (RTZ). SAFE because l is MFMA-accumulated from the SAME
// truncated pa registers as O -- quotient bias cancels (verified r16).
__device__ __forceinline__ unsigned cvt_pk_bf16(float a, float b) {
    unsigned r;
    asm("v_cvt_pk_bf16_f32 %0, %1, %2" : "=v"(r) : "v"(a), "v"(b));
    return r;
}
__device__ __forceinline__ f32x4 mfma16x16x16_bf16(s16x4 a, s16x4 b, f32x4 c) {
#if __has_builtin(__builtin_amdgcn_mfma_f32_16x16x16bf16_1k)
    return __builtin_amdgcn_mfma_f32_16x16x16bf16_1k(a, b, c, 0, 0, 0);
#else
    f32x4 d = c;
    asm volatile("v_mfma_f32_16x16x16_bf16 %0, %1, %2, %0" : "+v"(d) : "v"(a), "v"(b));
    return d;
#endif
}

// async global->LDS, 16B per lane; LDS dest = wave-uniform base + lane*16
__device__ __forceinline__ void gload16(const void* g, void* l) {
    __builtin_amdgcn_global_load_lds(
        (const __attribute__((address_space(1))) unsigned int*)g,
        (__attribute__((address_space(3))) unsigned int*)l, 16, 0, 0);
}

// ---------------- FUSED prologue: weight transposes + x convert + bias pack ----------------
// z=0: Wq -> wqkvT rows 0..2047    z=1: Wk -> rows 2048..2559   z=2: Wv -> rows 2560..3071
// z=3: Wo -> woT                   z=4,5: x fp32 -> bf16 (4096 blocks each)
// z=6: bias pack (12 active blocks)
__global__ __launch_bounds__(256) void prologue_kernel(
    const float* __restrict__ x, u16* __restrict__ xb,
    const float* __restrict__ Wq, const float* __restrict__ Wk,
    const float* __restrict__ Wv, const float* __restrict__ Wo,
    u16* __restrict__ wqkvT, u16* __restrict__ woT,
    const float* __restrict__ bq, const float* __restrict__ bk,
    const float* __restrict__ bv, float* __restrict__ biasQ) {
    int z = blockIdx.z;
    int tx = threadIdx.x;   // 0..31
    int ty = threadIdx.y;   // 0..7
    int tid = ty * 32 + tx; // flat 0..255

    if (z >= 4) {
        int bi = (int)blockIdx.y * 64 + (int)blockIdx.x;   // 0..4095 within slice
        if (z == 6) {
            // bias pack: 3072 elements in 12 blocks (r20 bug: bi had +8192 offset)
            if (bi >= 12) return;
            int i = bi * 256 + tid;
            if (i >= NQKV_) return;
            float v;
            if (i < 2048) v = bq[i];
            else if (i < 2560) v = bk[i - 2048];
            else v = bv[i - 2560];
            biasQ[i] = v;
        } else {
            // convert x: 2097152 float4s in 8192 blocks (z=4,5)
            int i = ((z - 4) * 4096 + bi) * 256 + tid;     // < 2097152 exactly
            f32x4 v = *(const f32x4*)(x + (size_t)i * 4);
            u16x4 o;
            o[0] = bf16rne(v[0]); o[1] = bf16rne(v[1]);
            o[2] = bf16rne(v[2]); o[3] = bf16rne(v[3]);
            *(u16x4*)(xb + (size_t)i * 4) = o;
        }
        return;
    }

    __shared__ float tile[32][33];
    const float* src; u16* dst; int N;
    if (z == 0)      { src = Wq; dst = wqkvT;                          N = 2048; }
    else if (z == 1) { src = Wk; dst = wqkvT + (size_t)2048 * 2048;    N = 512;  }
    else if (z == 2) { src = Wv; dst = wqkvT + (size_t)2560 * 2048;    N = 512;  }
    else             { src = Wo; dst = woT;                            N = 2048; }
    int n0 = blockIdx.x * 32;
    if (n0 >= N) return;
    int k0 = blockIdx.y * 32;
    for (int i = 0; i < 32; i += 8)
        tile[ty + i][tx] = src[(size_t)(k0 + ty + i) * N + n0 + tx];
    __syncthreads();
    for (int i = 0; i < 32; i += 8)
        dst[(size_t)(n0 + ty + i) * 2048 + k0 + tx] = bf16rne(tile[tx][ty + i]);
}

// ---------------- bf16 GEMM (m97 structure + T1 XCD swizzle) ----------------
template <bool OUT_BF16, bool FUSE_VT>
__global__ __launch_bounds__(256) void gemm_bt_kernel(const u16* __restrict__ A,
                                                      const u16* __restrict__ Bt,
                                                      const float* __restrict__ bias,
                                                      void* __restrict__ Cout,
                                                      u16* __restrict__ vTp,
                                                      int M, int N, int K) {
    __shared__ u16 As[128][64];
    __shared__ u16 Bs[128][64];
    int nwg = (int)(gridDim.x * gridDim.y);
    int bid = (int)(blockIdx.y * gridDim.x + blockIdx.x);
    int swz = (bid & 7) * (nwg >> 3) + (bid >> 3);
    int bn = (swz % (int)gridDim.x) * 128;
    int bm = (swz / (int)gridDim.x) * 128;
    int tid = threadIdx.x;
    int lane = tid & 63, wid = tid >> 6;
    int wr = wid >> 1, wc = wid & 1;
    int lr = lane & 15, lg = lane >> 4;
    f32x4 acc[4][4] = {};

    int srow_l = lane >> 3;
    int schunk = (lane & 7) ^ srow_l;
    int scol = schunk * 8;

    for (int k0 = 0; k0 < K; k0 += 64) {
        __syncthreads();
#pragma unroll
        for (int c = 0; c < 4; c++) {
            int row = c * 32 + wid * 8;
            gload16(A + (size_t)(bm + row + srow_l) * K + k0 + scol, &As[row][0]);
            gload16(Bt + (size_t)(bn + row + srow_l) * K + k0 + scol, &Bs[row][0]);
        }
        asm volatile("s_waitcnt vmcnt(0)" ::: "memory");
        __syncthreads();
#pragma unroll
        for (int kk = 0; kk < 2; kk++) {
            s16x8 a[4], b[4];
#pragma unroll
            for (int mi = 0; mi < 4; mi++) {
                int row = wr * 64 + mi * 16 + lr;
                int cc = ((kk << 2) + lg) ^ (lr & 7);
                a[mi] = *(const s16x8*)&As[row][cc << 3];
            }
#pragma unroll
            for (int ni = 0; ni < 4; ni++) {
                int row = wc * 64 + ni * 16 + lr;
                int cc = ((kk << 2) + lg) ^ (lr & 7);
                b[ni] = *(const s16x8*)&Bs[row][cc << 3];
            }
#pragma unroll
            for (int mi = 0; mi < 4; mi++)
#pragma unroll
                for (int ni = 0; ni < 4; ni++)
                    acc[mi][ni] = __builtin_amdgcn_mfma_f32_16x16x32_bf16(a[mi], b[ni], acc[mi][ni], 0, 0, 0);
        }
    }

#pragma unroll
    for (int mi = 0; mi < 4; mi++)
#pragma unroll
        for (int ni = 0; ni < 4; ni++) {
            int col = bn + wc * 64 + ni * 16 + lr;
            float bsv = bias ? bias[col] : 0.0f;
            int row0 = bm + wr * 64 + mi * 16 + lg * 4;
            if (FUSE_VT && col >= 2560) {
                int kvd = col - 2560;
                int bq_ = row0 >> 11;
                int s0 = row0 & 2047;
                u16x4 w;
#pragma unroll
                for (int r = 0; r < 4; r++) w[r] = bf16rne(acc[mi][ni][r] + bsv);
                *(u16x4*)(vTp + (size_t)(bq_ * 8 * 64 + kvd) * 2048 + s0) = w;
            } else {
#pragma unroll
                for (int r = 0; r < 4; r++) {
                    float v = acc[mi][ni][r] + bsv;
                    if (OUT_BF16)
                        ((u16*)Cout)[(size_t)(row0 + r) * N + col] = bf16rne(v);
                    else
                        ((float*)Cout)[(size_t)(row0 + r) * N + col] = v;
                }
            }
        }
}

// ---------------- flash attention (r16 config -- validated 93.5us) ----------------
__global__ __launch_bounds__(512) void attn_kernel(const u16* __restrict__ qkv,
                                                   const u16* __restrict__ vT,
                                                   u16* __restrict__ attn_out) {
    int bx = blockIdx.x;             // 0..31
    int bkv = blockIdx.y;            // 0..15
    int b = bkv >> 3, kvh = bkv & 7;
    int tid = threadIdx.x;
    int lane = tid & 63, wid = tid >> 6;   // 8 waves
    int lr = lane & 15, lg = lane >> 4;
    int h = kvh * 4 + (wid >> 1);    // q head: 2 waves per head
    int sub = wid & 1;               // 16-row subtile within the 32-row q-tile

    __shared__ u16 Ks[2][64][72];    // [buf][kv][d] padded (144B stride)
    __shared__ u16 Vs[2][64][72];    // [buf][d][kv] padded

    const u16* Kbase = qkv + (size_t)(b * S_) * NQKV_ + 2048 + kvh * 64;
    const u16* Vbase = vT + (size_t)(b * 8 + kvh) * 64 * S_;

    int srow = tid >> 3;             // 0..63 (one staging pass, 512 threads)
    int scol = (tid & 7) * 8;

    // ones A-fragment for the l-row: A[row=lr][k] = (lr==0) ? 1.0bf16 : 0
    s16x4 ones = {};
    if (lr == 0) {
        ones[0] = (short)0x3F80; ones[1] = (short)0x3F80;
        ones[2] = (short)0x3F80; ones[3] = (short)0x3F80;
    }

#pragma unroll 1
    for (int phase = 0; phase < 2; phase++) {
        int qt = phase ? (63 - bx) : bx;   // 32-row q-tile index
        int qrow0 = qt * 32 + sub * 16;    // this wave's first q row
        int nt = qt / 2 + 1;               // kv tiles of 64 covering causal extent

        // Q as B-fragment: lane holds Q[q=lr][d = db*32 + lg*8 + j], prescaled
        s16x8 qf[2];
        {
            const u16* qr = qkv + (size_t)(b * S_ + qrow0 + lr) * NQKV_ + h * 64;
#pragma unroll
            for (int db = 0; db < 2; db++) {
                u16x8 u = *(const u16x8*)(qr + db * 32 + lg * 8);
                s16x8 s;
#pragma unroll
                for (int j = 0; j < 8; j++) s[j] = (short)bf16rne(bf16tof(u[j]) * 0.18033688f);
                qf[db] = s;
            }
        }

        f32x4 O[4] = {};                 // O^T: O[dt] reg r = O[q=lr][d = 16dt + 4lg + r]
        f32x4 lacc = {};                 // l-row accumulator (lane lr at lg==0, reg 0)
        float m_i = -1e30f;              // running max for q-row (qrow0 + lr)

        // prologue: stage kv tile 0 into buf 0
        {
            u16x8 k0v = *(const u16x8*)(Kbase + (size_t)srow * NQKV_ + scol);
            u16x8 v0v = *(const u16x8*)(Vbase + (size_t)srow * S_ + scol);
            *(u16x8*)&Ks[0][srow][scol] = k0v;
            *(u16x8*)&Vs[0][srow][scol] = v0v;
        }
        __syncthreads();

        int cb = 0;
        for (int t = 0; t < nt; t++) {
            int kv0 = t * 64;
            bool notlast = (t + 1 < nt);
            // T14: issue next tile's global loads early (hide HBM/L2 under compute)
            u16x8 kn, vn;
            if (notlast) {
                kn = *(const u16x8*)(Kbase + (size_t)(kv0 + 64 + srow) * NQKV_ + scol);
                vn = *(const u16x8*)(Vbase + (size_t)srow * S_ + kv0 + 64 + scol);
            }

            // swapped QK^T: Sc[t4][r] = S[kv0+16t4+4lg+r][qrow0+lr]
            f32x4 Sc[4] = {};
            __builtin_amdgcn_s_setprio(1);
#pragma unroll
            for (int t4 = 0; t4 < 4; t4++) {
#pragma unroll
                for (int db = 0; db < 2; db++) {
                    s16x8 kf = *(const s16x8*)&Ks[cb][t4 * 16 + lr][db * 32 + lg * 8];
                    Sc[t4] = __builtin_amdgcn_mfma_f32_16x16x32_bf16(kf, qf[db], Sc[t4], 0, 0, 0);
                }
            }
            __builtin_amdgcn_s_setprio(0);
            // causal mask: only last tile is partial (block-uniform branch)
            if (t == nt - 1) {
                int qr = qrow0 + lr;
#pragma unroll
                for (int t4 = 0; t4 < 4; t4++)
#pragma unroll
                    for (int r = 0; r < 4; r++) {
                        int kvi = kv0 + t4 * 16 + lg * 4 + r;
                        Sc[t4][r] = (kvi <= qr) ? Sc[t4][r] : -1e30f;
                    }
            }
            // lane-local online softmax for q-row (qrow0+lr)
            f32x4 mm = vmax4(vmax4(Sc[0], Sc[1]), vmax4(Sc[2], Sc[3]));
            float mx = fmaxf(fmaxf(mm[0], mm[1]), fmaxf(mm[2], mm[3]));
            mx = fmaxf(mx, __shfl_xor(mx, 16));
            mx = fmaxf(mx, __shfl_xor(mx, 32));
            // skip-rescale: only when some lane's max grew (alpha==1 exactly otherwise)
            if (__any(mx > m_i)) {
                float newm = fmaxf(m_i, mx);
                float alpha = exp2f(m_i - newm);
                m_i = newm;
#pragma unroll
                for (int dt = 0; dt < 4; dt++)
#pragma unroll
                    for (int r = 0; r < 4; r++) O[dt][r] *= alpha;
#pragma unroll
                for (int r = 0; r < 4; r++) lacc[r] *= alpha;
            }
            f32x4 p4[4];
#pragma unroll
            for (int t4 = 0; t4 < 4; t4++)
#pragma unroll
                for (int r = 0; r < 4; r++)
                    p4[t4][r] = exp2f(Sc[t4][r] - m_i);
            // pack P via cvt_pk (8 ops); l comes from MFMA below using the same regs
            s16x4 pa[4];
#pragma unroll
            for (int t4 = 0; t4 < 4; t4++) {
                union { unsigned u[2]; s16x4 v; } uu;
                uu.u[0] = cvt_pk_bf16(p4[t4][0], p4[t4][1]);
                uu.u[1] = cvt_pk_bf16(p4[t4][2], p4[t4][3]);
                pa[t4] = uu.v;
            }
            // PV transposed: O^T += V^T * P; plus l-row via ones A-fragment
            __builtin_amdgcn_s_setprio(1);
#pragma unroll
            for (int t4 = 0; t4 < 4; t4++) {
#pragma unroll
                for (int dt = 0; dt < 4; dt++) {
                    s16x4 va = *(const s16x4*)&Vs[cb][dt * 16 + lr][t4 * 16 + lg * 4];
                    O[dt] = mfma16x16x16_bf16(va, pa[t4], O[dt]);
                }
                lacc = mfma16x16x16_bf16(ones, pa[t4], lacc);
            }
            __builtin_amdgcn_s_setprio(0);
            // write staged regs to the other buffer (nobody reads it this iter)
            if (notlast) {
                *(u16x8*)&Ks[cb ^ 1][srow][scol] = kn;
                *(u16x8*)&Vs[cb ^ 1][srow][scol] = vn;
            }
            __syncthreads();         // single barrier: staging visible + reads done
            cb ^= 1;
        }

        // epilogue: l[q=lr] lives at lane lr (lg==0), reg 0 of lacc
        float lv = __shfl(lacc[0], lr);
        float il = 1.0f / lv;
        u16* orow = attn_out + (size_t)(b * S_ + qrow0 + lr) * HID_ + h * 64 + lg * 4;
#pragma unroll
        for (int dt = 0; dt < 4; dt++) {
            u16x4 w;
#pragma unroll
            for (int r = 0; r < 4; r++) w[r] = bf16rne(O[dt][r] * il);
            *(u16x4*)(orow + dt * 16) = w;
        }
    }
}

extern "C" void kernel_launch(void* const* d_in, const int* in_sizes, int n_in,
                              void* d_out, int out_size, void* d_ws, size_t ws_size,
                              hipStream_t stream) {
    const float* x  = (const float*)d_in[0];
    // d_in[1] = mask (causal, implemented structurally)
    const float* Wq = (const float*)d_in[2];
    const float* bq = (const float*)d_in[3];
    const float* Wk = (const float*)d_in[4];
    const float* bk = (const float*)d_in[5];
    const float* Wv = (const float*)d_in[6];
    const float* bv = (const float*)d_in[7];
    const float* Wo = (const float*)d_in[8];
    const float* bo = (const float*)d_in[9];
    float* out = (float*)d_out;

    char* ws = (char*)d_ws;
    u16* xb     = (u16*)(ws);                              // 16.78 MB
    u16* wqkvT  = (u16*)(ws + 16777216);                   // 12.58 MB
    u16* woT    = (u16*)(ws + 29360128);                   // 8.39 MB
    u16* qkv    = (u16*)(ws + 37748736);                   // 25.17 MB
    u16* vT     = (u16*)(ws + 62914560);                   // 4.19 MB
    u16* attnO  = (u16*)(ws + 67108864);                   // 16.78 MB
    float* biasQ = (float*)(ws + 83886080);                // 12 KB

    // 1. fused prologue: weight transposes + x convert + bias pack (one dispatch)
    prologue_kernel<<<dim3(64, 64, 7), dim3(32, 8), 0, stream>>>(
        x, xb, Wq, Wk, Wv, Wo, wqkvT, woT, bq, bk, bv, biasQ);
    // 2. QKV GEMM (V slice -> vT directly)
    gemm_bt_kernel<true, true><<<dim3(NQKV_ / 128, M_ / 128), 256, 0, stream>>>(
        xb, wqkvT, biasQ, qkv, vT, M_, NQKV_, HID_);
    // 3. attention (r16 config): 512 blocks, KVBLK=64, paired causal q-tiles
    attn_kernel<<<dim3(32, B_ * NKV_), 512, 0, stream>>>(qkv, vT, attnO);
    // 4. output GEMM (m97 128^2 structure)
    gemm_bt_kernel<false, false><<<dim3(HID_ / 128, M_ / 128), 256, 0, stream>>>(
        attnO, woT, bo, out, nullptr, M_, HID_, HID_);
}